// Round 1
// baseline (695.585 us; speedup 1.0000x reference)
//
#include <hip/hip_runtime.h>
#include <math.h>

// Problem constants
#define NB 32768        // batch rows
#define ND 768          // embedding dim
#define NH 256          // hidden
#define NH2 128         // hidden/2
#define NG 8            // groups
#define GSZ 96          // group size

__device__ __forceinline__ float gelu_exact(float v) {
    return 0.5f * v * (1.0f + erff(v * 0.7071067811865475f));
}

// ---------------------------------------------------------------------------
// K1: u = x @ [w1 | dw1]  (32 rows x 512 cols per block), then
//     h1 = gelu(LayerNorm(u[:, :256] + b1))   g1 = gelu(u[:, 256:] + db1)
// ---------------------------------------------------------------------------
__global__ __launch_bounds__(256, 2) void k1_gemm_lnx(
    const float* __restrict__ x, const float* __restrict__ w1,
    const float* __restrict__ dw1, const float* __restrict__ b1,
    const float* __restrict__ db1, const float* __restrict__ lng,
    const float* __restrict__ lnb, float* __restrict__ h1out,
    float* __restrict__ g1out)
{
    __shared__ float xs[32][36];     // [k][row], padded for float4 align, 2-way banks
    __shared__ float ws[32][512];    // [k][col 0..511]  (64 KiB)
    __shared__ float psum[32][33];
    __shared__ float psq[32][33];
    __shared__ float smean[32];
    __shared__ float srstd[32];

    const int tid = threadIdx.x;
    const int tc = tid & 63;         // 64 col-threads (wave lanes)
    const int tr = tid >> 6;         // 4 row-threads (one per wave)
    const int c0 = tc * 8;           // col base within 512
    const int r0 = tr * 8;           // row base within 32
    const int rowsBase = blockIdx.x * 32;

    float acc[8][8];
    #pragma unroll
    for (int i = 0; i < 8; ++i)
        #pragma unroll
        for (int j = 0; j < 8; ++j) acc[i][j] = 0.0f;

    for (int kb = 0; kb < ND; kb += 32) {
        // stage x tile: 32 rows x 32 k, transposed to xs[k][row]
        {
            int r = tid & 31, i = tid >> 5;  // i in 0..7
            float4 v = *(const float4*)(x + (size_t)(rowsBase + r) * ND + kb + i * 4);
            xs[i*4+0][r] = v.x; xs[i*4+1][r] = v.y; xs[i*4+2][r] = v.z; xs[i*4+3][r] = v.w;
        }
        // stage weights: 32 k x 512 cols (w1 cols 0..255, dw1 cols 256..511)
        #pragma unroll
        for (int m = 0; m < 16; ++m) {
            int flat4 = m * 256 + tid;
            int k = flat4 >> 7;
            int c = (flat4 & 127) * 4;
            float4 v;
            if (c < 256) v = *(const float4*)(w1  + (size_t)(kb + k) * 256 + c);
            else         v = *(const float4*)(dw1 + (size_t)(kb + k) * 256 + (c - 256));
            *(float4*)&ws[k][c] = v;
        }
        __syncthreads();
        #pragma unroll 4
        for (int k = 0; k < 32; ++k) {
            float xv[8], wv[8];
            *(float4*)&xv[0] = *(const float4*)&xs[k][r0];       // wave-uniform: broadcast
            *(float4*)&xv[4] = *(const float4*)&xs[k][r0 + 4];
            *(float4*)&wv[0] = *(const float4*)&ws[k][c0];
            *(float4*)&wv[4] = *(const float4*)&ws[k][c0 + 4];
            #pragma unroll
            for (int i = 0; i < 8; ++i)
                #pragma unroll
                for (int j = 0; j < 8; ++j)
                    acc[i][j] = fmaf(xv[i], wv[j], acc[i][j]);
        }
        __syncthreads();
    }

    const bool isW1 = (tc < 32);
    const int ccol = isW1 ? c0 : (c0 - 256);

    #pragma unroll
    for (int j = 0; j < 8; ++j) {
        float bv = isW1 ? b1[ccol + j] : db1[ccol + j];
        #pragma unroll
        for (int i = 0; i < 8; ++i) acc[i][j] += bv;
    }

    if (isW1) {
        #pragma unroll
        for (int i = 0; i < 8; ++i) {
            float s = 0.0f, q = 0.0f;
            #pragma unroll
            for (int j = 0; j < 8; ++j) { s += acc[i][j]; q += acc[i][j] * acc[i][j]; }
            psum[r0 + i][tc] = s;
            psq [r0 + i][tc] = q;
        }
    }
    __syncthreads();
    if (tid < 32) {
        float s = 0.0f, q = 0.0f;
        for (int t = 0; t < 32; ++t) { s += psum[tid][t]; q += psq[tid][t]; }
        float mean = s * (1.0f / 256.0f);
        float var  = q * (1.0f / 256.0f) - mean * mean;
        smean[tid] = mean;
        srstd[tid] = rsqrtf(var + 1e-5f);
    }
    __syncthreads();

    if (isW1) {
        #pragma unroll
        for (int i = 0; i < 8; ++i) {
            int row = rowsBase + r0 + i;
            float mean = smean[r0 + i], rstd = srstd[r0 + i];
            float o[8];
            #pragma unroll
            for (int j = 0; j < 8; ++j) {
                float v = (acc[i][j] - mean) * rstd * lng[ccol + j] + lnb[ccol + j];
                o[j] = gelu_exact(v);
            }
            *(float4*)(h1out + (size_t)row * 256 + ccol)     = *(float4*)&o[0];
            *(float4*)(h1out + (size_t)row * 256 + ccol + 4) = *(float4*)&o[4];
        }
    } else {
        #pragma unroll
        for (int i = 0; i < 8; ++i) {
            int row = rowsBase + r0 + i;
            float o[8];
            #pragma unroll
            for (int j = 0; j < 8; ++j) o[j] = gelu_exact(acc[i][j]);
            *(float4*)(g1out + (size_t)row * 256 + ccol)     = *(float4*)&o[0];
            *(float4*)(g1out + (size_t)row * 256 + ccol + 4) = *(float4*)&o[4];
        }
    }
}

// ---------------------------------------------------------------------------
// K2: C = act(A[*,256] @ W[256,N] + bias), tile 64 rows x 128 cols.
// ACT==0: gelu (h2), ACT==1: sigmoid (dim_weights)
// ---------------------------------------------------------------------------
template<int ACT>
__global__ __launch_bounds__(256, 2) void k2_gemm(
    const float* __restrict__ A, const float* __restrict__ W,
    const float* __restrict__ bias, float* __restrict__ out,
    int N, int colBlocks)
{
    __shared__ float xs[32][72];     // [k][row 0..63]
    __shared__ float ws[32][128];

    const int tid = threadIdx.x;
    const int tc = tid & 31;         // 32 col-threads, 4 cols each
    const int tr = tid >> 5;         // 8 row-threads, 8 rows each
    const int c0 = tc * 4;
    const int r0 = tr * 8;
    const int rb = blockIdx.x / colBlocks;
    const int cb = blockIdx.x % colBlocks;
    const int rowsBase = rb * 64;
    const int colBase = cb * 128;

    float acc[8][4];
    #pragma unroll
    for (int i = 0; i < 8; ++i)
        #pragma unroll
        for (int j = 0; j < 4; ++j) acc[i][j] = 0.0f;

    for (int kb = 0; kb < 256; kb += 32) {
        #pragma unroll
        for (int m = 0; m < 2; ++m) {
            int r = tid & 63, i = (tid >> 6) + m * 4;   // i in 0..7
            float4 v = *(const float4*)(A + (size_t)(rowsBase + r) * 256 + kb + i * 4);
            xs[i*4+0][r] = v.x; xs[i*4+1][r] = v.y; xs[i*4+2][r] = v.z; xs[i*4+3][r] = v.w;
        }
        #pragma unroll
        for (int m = 0; m < 4; ++m) {
            int flat4 = m * 256 + tid;
            int k = flat4 >> 5;
            int c = (flat4 & 31) * 4;
            *(float4*)&ws[k][c] = *(const float4*)(W + (size_t)(kb + k) * N + colBase + c);
        }
        __syncthreads();
        #pragma unroll 4
        for (int k = 0; k < 32; ++k) {
            float xv[8], wv[4];
            *(float4*)&xv[0] = *(const float4*)&xs[k][r0];
            *(float4*)&xv[4] = *(const float4*)&xs[k][r0 + 4];
            *(float4*)&wv[0] = *(const float4*)&ws[k][c0];
            #pragma unroll
            for (int i = 0; i < 8; ++i)
                #pragma unroll
                for (int j = 0; j < 4; ++j)
                    acc[i][j] = fmaf(xv[i], wv[j], acc[i][j]);
        }
        __syncthreads();
    }

    float bv[4];
    #pragma unroll
    for (int j = 0; j < 4; ++j) bv[j] = bias[colBase + c0 + j];
    #pragma unroll
    for (int i = 0; i < 8; ++i) {
        int row = rowsBase + r0 + i;
        float o[4];
        #pragma unroll
        for (int j = 0; j < 4; ++j) {
            float v = acc[i][j] + bv[j];
            o[j] = (ACT == 0) ? gelu_exact(v) : (1.0f / (1.0f + expf(-v)));
        }
        *(float4*)(out + (size_t)row * N + colBase + c0) = *(float4*)&o[0];
    }
}

// ---------------------------------------------------------------------------
// K3: logits = h2 @ w3 + b3 + gi; probs; constrained selection; group_mask;
//     scalar partials. One thread per row, 256 rows per block.
// scal layout: [0]=active_groups [1..8]=group_usage [9]=load_balance [10]=active_dims
// ---------------------------------------------------------------------------
__global__ __launch_bounds__(256) void k3_router(
    const float* __restrict__ h2, const float* __restrict__ w3,
    const float* __restrict__ b3, const float* __restrict__ gi,
    float* __restrict__ probsOut, float* __restrict__ selOut,
    float* __restrict__ gmaskOut, float* __restrict__ scal)
{
    __shared__ float ws3[128][8];
    __shared__ float smask[256][8];
    __shared__ float sAct[4], sP[4], sCnt[4][8];

    const int tid = threadIdx.x;
    {
        int k = tid >> 1, goff = (tid & 1) * 4;
        *(float4*)&ws3[k][goff] = *(const float4*)(w3 + k * 8 + goff);
    }
    __syncthreads();

    const int row = blockIdx.x * 256 + tid;
    const float* h2r = h2 + (size_t)row * 128;

    float accg[8];
    #pragma unroll
    for (int g = 0; g < 8; ++g) accg[g] = 0.0f;
    #pragma unroll 8
    for (int k4 = 0; k4 < 32; ++k4) {
        float4 hv = *(const float4*)(h2r + k4 * 4);
        float hv4[4] = {hv.x, hv.y, hv.z, hv.w};
        #pragma unroll
        for (int t = 0; t < 4; ++t)
            #pragma unroll
            for (int g = 0; g < 8; ++g)
                accg[g] = fmaf(hv4[t], ws3[k4 * 4 + t][g], accg[g]);
    }

    float p[8], gs[8], cnt[8];
    float actCnt = 0.0f, pSum = 0.0f;
    #pragma unroll
    for (int g = 0; g < 8; ++g) {
        float lg = accg[g] + b3[g] + gi[g];
        p[g] = 1.0f / (1.0f + expf(-lg));
    }
    #pragma unroll
    for (int g = 0; g < 8; ++g) {
        int rank = 0;
        #pragma unroll
        for (int j = 0; j < 8; ++j) {
            rank += (p[j] > p[g]) ? 1 : 0;
            rank += (j < g && p[j] == p[g]) ? 1 : 0;   // stable-sort tie break
        }
        float act = (rank < 2) ? 1.0f
                  : ((rank < 6) ? ((p[g] > 0.5f) ? 1.0f : 0.0f) : 0.0f);
        gs[g] = (act - p[g]) + p[g];                   // STE forward value, ulp-exact
        float over = (p[g] > 0.5f) ? 1.0f : 0.0f;
        cnt[g] = over;
        actCnt += over;
        pSum += p[g];
        smask[tid][g] = gs[g];
    }

    *(float4*)(probsOut + (size_t)row * 8)     = *(float4*)&p[0];
    *(float4*)(probsOut + (size_t)row * 8 + 4) = *(float4*)&p[4];
    *(float4*)(selOut   + (size_t)row * 8)     = *(float4*)&gs[0];
    *(float4*)(selOut   + (size_t)row * 8 + 4) = *(float4*)&gs[4];

    // wave-level reductions
    #pragma unroll
    for (int o = 32; o > 0; o >>= 1) {
        actCnt += __shfl_down(actCnt, o);
        pSum   += __shfl_down(pSum, o);
        #pragma unroll
        for (int g = 0; g < 8; ++g) cnt[g] += __shfl_down(cnt[g], o);
    }
    if ((tid & 63) == 0) {
        int w = tid >> 6;
        sAct[w] = actCnt; sP[w] = pSum;
        #pragma unroll
        for (int g = 0; g < 8; ++g) sCnt[w][g] = cnt[g];
    }
    __syncthreads();   // also guarantees smask is complete
    if (tid == 0) {
        const float invB = 1.0f / 32768.0f;
        atomicAdd(&scal[0], (sAct[0] + sAct[1] + sAct[2] + sAct[3]) * invB);
        atomicAdd(&scal[9], (sP[0] + sP[1] + sP[2] + sP[3]) * invB);
        #pragma unroll
        for (int g = 0; g < 8; ++g)
            atomicAdd(&scal[1 + g],
                      (sCnt[0][g] + sCnt[1][g] + sCnt[2][g] + sCnt[3][g]) * invB);
    }

    // cooperative coalesced group_mask write: 256 rows x 768 cols
    const int rowsBase = blockIdx.x * 256;
    for (int m = 0; m < 192; ++m) {
        int idx4 = m * 256 + tid;
        int rloc = idx4 / 192;            // 192 float4 per row
        int c4 = idx4 - rloc * 192;
        int c = c4 * 4;
        int g = c / 96;                    // 4 consecutive floats never cross a group
        float v = smask[rloc][g];
        float4 o = {v, v, v, v};
        *(float4*)(gmaskOut + (size_t)(rowsBase + rloc) * 768 + c) = o;
    }
}

// ---------------------------------------------------------------------------
// K4: mask = group_mask * dim_weights; active_dims = mean_B count(mask > 0.5)
// ---------------------------------------------------------------------------
__global__ __launch_bounds__(256) void k4_mask(
    const float* __restrict__ gmask, const float* __restrict__ dwts,
    float* __restrict__ maskOut, float* __restrict__ activeDims)
{
    const int stride = gridDim.x * 256;
    float cnt = 0.0f;
    for (int i4 = blockIdx.x * 256 + threadIdx.x; i4 < 6291456; i4 += stride) {
        float4 g = *(const float4*)(gmask + (size_t)i4 * 4);
        float4 d = *(const float4*)(dwts + (size_t)i4 * 4);
        float4 m = {g.x * d.x, g.y * d.y, g.z * d.z, g.w * d.w};
        *(float4*)(maskOut + (size_t)i4 * 4) = m;
        cnt += (m.x > 0.5f ? 1.0f : 0.0f) + (m.y > 0.5f ? 1.0f : 0.0f)
             + (m.z > 0.5f ? 1.0f : 0.0f) + (m.w > 0.5f ? 1.0f : 0.0f);
    }
    #pragma unroll
    for (int o = 32; o > 0; o >>= 1) cnt += __shfl_down(cnt, o);
    __shared__ float sc[4];
    if ((threadIdx.x & 63) == 0) sc[threadIdx.x >> 6] = cnt;
    __syncthreads();
    if (threadIdx.x == 0)
        atomicAdd(activeDims, (sc[0] + sc[1] + sc[2] + sc[3]) * (1.0f / 32768.0f));
}

__global__ void kz_zero(float* s) { if (threadIdx.x < 11) s[threadIdx.x] = 0.0f; }

// ---------------------------------------------------------------------------
extern "C" void kernel_launch(void* const* d_in, const int* in_sizes, int n_in,
                              void* d_out, int out_size, void* d_ws, size_t ws_size,
                              hipStream_t stream)
{
    const float* x   = (const float*)d_in[0];
    const float* w1  = (const float*)d_in[1];
    const float* b1  = (const float*)d_in[2];
    const float* lng = (const float*)d_in[3];
    const float* lnb = (const float*)d_in[4];
    const float* w2  = (const float*)d_in[5];
    const float* b2  = (const float*)d_in[6];
    const float* w3  = (const float*)d_in[7];
    const float* b3  = (const float*)d_in[8];
    const float* dw1 = (const float*)d_in[9];
    const float* db1 = (const float*)d_in[10];
    const float* dw2 = (const float*)d_in[11];
    const float* db2 = (const float*)d_in[12];
    const float* gi  = (const float*)d_in[13];

    float* out   = (float*)d_out;
    float* mask  = out;                 // [B,768]
    float* gmask = out + 25165824;      // [B,768]
    float* dwts  = out + 50331648;      // [B,768]
    float* probs = out + 75497472;      // [B,8]
    float* sel   = out + 75759616;      // [B,8]
    float* scal  = out + 76021760;      // 11 scalars

    // scratch inside the mask slot (overwritten by k4 last)
    float* h1 = mask;                   // [B,256] floats 0 .. 8388607
    float* g1 = mask + 8388608;         // [B,256]
    float* h2 = mask + 16777216;        // [B,128]

    kz_zero<<<dim3(1), dim3(64), 0, stream>>>(scal);
    k1_gemm_lnx<<<dim3(1024), dim3(256), 0, stream>>>(
        x, w1, dw1, b1, db1, lng, lnb, h1, g1);
    k2_gemm<0><<<dim3(512), dim3(256), 0, stream>>>(h1, w2, b2, h2, 128, 1);
    k2_gemm<1><<<dim3(3072), dim3(256), 0, stream>>>(g1, dw2, db2, dwts, 768, 6);
    k3_router<<<dim3(128), dim3(256), 0, stream>>>(
        h2, w3, b3, gi, probs, sel, gmask, scal);
    k4_mask<<<dim3(2048), dim3(256), 0, stream>>>(gmask, dwts, mask, &scal[10]);
}

// Round 2
// 660.963 us; speedup vs baseline: 1.0524x; 1.0524x over previous
//
#include <hip/hip_runtime.h>
#include <math.h>

#define NB 32768
#define ND 768
#define NH 256
#define NG 8
#define GSZ 96

__device__ __forceinline__ float gelu_exact(float v) {
    return 0.5f * v * (1.0f + erff(v * 0.7071067811865475f));
}

// ---------------------------------------------------------------------------
// K1: u = x @ [w1 | dw1] ; h1 = gelu(LN(u_w1 + b1)) ; g1 = gelu(u_dw1 + db1)
// 512 threads, tile 64 rows x 512 cols, K-chunk 32.
// Thread (tc=tid&63, wv=tid>>6): rows wv*8..+7, cols {tc*4..+3} of each half.
// ws reads: 64 lanes read 64 consecutive float4 -> conflict-free.
// xs reads: wave-uniform (wv constant per wave) -> broadcast.
// ---------------------------------------------------------------------------
__global__ __launch_bounds__(512, 4) void k1_gemm_lnx(
    const float* __restrict__ x, const float* __restrict__ w1,
    const float* __restrict__ dw1, const float* __restrict__ b1,
    const float* __restrict__ db1, const float* __restrict__ lng,
    const float* __restrict__ lnb, float* __restrict__ h1out,
    float* __restrict__ g1out)
{
    __shared__ float xs[32][64];     // [k][row]  8 KB
    __shared__ float ws[32][512];    // [k][col]  64 KB  (cols 0..255 w1, 256..511 dw1)

    const int tid = threadIdx.x;
    const int tc = tid & 63;
    const int wv = tid >> 6;         // wave id == row-group
    const int c0 = tc * 4;           // col base within each 256-half
    const int r0 = wv * 8;
    const int rowsBase = blockIdx.x * 64;

    float acc[8][8];                 // [row i][j: 0-3 w1 cols c0+j, 4-7 dw1 cols c0+j-4]
    #pragma unroll
    for (int i = 0; i < 8; ++i)
        #pragma unroll
        for (int j = 0; j < 8; ++j) acc[i][j] = 0.0f;

    for (int kb = 0; kb < ND; kb += 32) {
        // stage x: 64 rows x 32 k -> xs[k][row]; 512 f4, one per thread
        {
            int r = tid >> 3, i4 = tid & 7;
            float4 v = *(const float4*)(x + (size_t)(rowsBase + r) * ND + kb + i4 * 4);
            xs[i4*4+0][r] = v.x; xs[i4*4+1][r] = v.y;
            xs[i4*4+2][r] = v.z; xs[i4*4+3][r] = v.w;
        }
        // stage weights: 32 k x 512 cols; 4096 f4, 8 per thread
        #pragma unroll
        for (int m = 0; m < 8; ++m) {
            int flat = m * 512 + tid;
            int k = flat >> 7;
            int c = (flat & 127) * 4;
            float4 v;
            if (c < 256) v = *(const float4*)(w1  + (size_t)(kb + k) * 256 + c);
            else         v = *(const float4*)(dw1 + (size_t)(kb + k) * 256 + (c - 256));
            *(float4*)&ws[k][c] = v;
        }
        __syncthreads();
        #pragma unroll 8
        for (int k = 0; k < 32; ++k) {
            float xv[8], wv4[8];
            *(float4*)&xv[0]  = *(const float4*)&xs[k][r0];        // broadcast
            *(float4*)&xv[4]  = *(const float4*)&xs[k][r0 + 4];    // broadcast
            *(float4*)&wv4[0] = *(const float4*)&ws[k][c0];        // conflict-free
            *(float4*)&wv4[4] = *(const float4*)&ws[k][256 + c0];  // conflict-free
            #pragma unroll
            for (int i = 0; i < 8; ++i)
                #pragma unroll
                for (int j = 0; j < 8; ++j)
                    acc[i][j] = fmaf(xv[i], wv4[j], acc[i][j]);
        }
        __syncthreads();
    }

    // biases
    float4 b1v  = *(const float4*)(b1 + c0);
    float4 db1v = *(const float4*)(db1 + c0);
    #pragma unroll
    for (int i = 0; i < 8; ++i) {
        acc[i][0] += b1v.x;  acc[i][1] += b1v.y;
        acc[i][2] += b1v.z;  acc[i][3] += b1v.w;
        acc[i][4] += db1v.x; acc[i][5] += db1v.y;
        acc[i][6] += db1v.z; acc[i][7] += db1v.w;
    }

    // LayerNorm stats over the 256 w1-cols of each row: intra-wave reduce
    float s[8], q[8];
    #pragma unroll
    for (int i = 0; i < 8; ++i) {
        s[i] = acc[i][0] + acc[i][1] + acc[i][2] + acc[i][3];
        q[i] = acc[i][0]*acc[i][0] + acc[i][1]*acc[i][1]
             + acc[i][2]*acc[i][2] + acc[i][3]*acc[i][3];
    }
    #pragma unroll
    for (int o = 1; o < 64; o <<= 1) {
        #pragma unroll
        for (int i = 0; i < 8; ++i) {
            s[i] += __shfl_xor(s[i], o);
            q[i] += __shfl_xor(q[i], o);
        }
    }

    float4 lngv = *(const float4*)(lng + c0);
    float4 lnbv = *(const float4*)(lnb + c0);
    #pragma unroll
    for (int i = 0; i < 8; ++i) {
        int row = rowsBase + r0 + i;
        float mean = s[i] * (1.0f / 256.0f);
        float var  = q[i] * (1.0f / 256.0f) - mean * mean;
        float rstd = rsqrtf(var + 1e-5f);
        float4 h;
        h.x = gelu_exact((acc[i][0] - mean) * rstd * lngv.x + lnbv.x);
        h.y = gelu_exact((acc[i][1] - mean) * rstd * lngv.y + lnbv.y);
        h.z = gelu_exact((acc[i][2] - mean) * rstd * lngv.z + lnbv.z);
        h.w = gelu_exact((acc[i][3] - mean) * rstd * lngv.w + lnbv.w);
        *(float4*)(h1out + (size_t)row * 256 + c0) = h;
        float4 g;
        g.x = gelu_exact(acc[i][4]); g.y = gelu_exact(acc[i][5]);
        g.z = gelu_exact(acc[i][6]); g.w = gelu_exact(acc[i][7]);
        *(float4*)(g1out + (size_t)row * 256 + c0) = g;
    }
}

// ---------------------------------------------------------------------------
// K2: C = act(A[*,256] @ W[256,N] + bias), tile 128 rows x 128 cols, 8x8/thread.
// ACT==0: gelu (h2), ACT==1: sigmoid (dim_weights)
// ---------------------------------------------------------------------------
template<int ACT>
__global__ __launch_bounds__(256, 4) void k2_gemm(
    const float* __restrict__ A, const float* __restrict__ W,
    const float* __restrict__ bias, float* __restrict__ out,
    int N, int colBlocks)
{
    __shared__ float xs[32][128];    // [k][row] 16 KB
    __shared__ float ws[32][128];    // 16 KB

    const int tid = threadIdx.x;
    const int tc = tid & 15;         // 16 col-threads x 8 cols (two 4-col blocks)
    const int tr = tid >> 4;         // 16 row-threads x 8 rows
    const int c0 = tc * 4;
    const int c1 = 64 + tc * 4;
    const int r0 = tr * 8;
    const int rb = blockIdx.x / colBlocks;
    const int cb = blockIdx.x % colBlocks;
    const int rowsBase = rb * 128;
    const int colBase = cb * 128;

    float acc[8][8];
    #pragma unroll
    for (int i = 0; i < 8; ++i)
        #pragma unroll
        for (int j = 0; j < 8; ++j) acc[i][j] = 0.0f;

    for (int kb = 0; kb < 256; kb += 32) {
        #pragma unroll
        for (int m = 0; m < 4; ++m) {
            int flat = m * 256 + tid;
            int r = flat >> 3, i4 = flat & 7;
            float4 v = *(const float4*)(A + (size_t)(rowsBase + r) * 256 + kb + i4 * 4);
            xs[i4*4+0][r] = v.x; xs[i4*4+1][r] = v.y;
            xs[i4*4+2][r] = v.z; xs[i4*4+3][r] = v.w;
        }
        #pragma unroll
        for (int m = 0; m < 4; ++m) {
            int flat = m * 256 + tid;
            int k = flat >> 5;
            int c = (flat & 31) * 4;
            *(float4*)&ws[k][c] = *(const float4*)(W + (size_t)(kb + k) * N + colBase + c);
        }
        __syncthreads();
        #pragma unroll 8
        for (int k = 0; k < 32; ++k) {
            float xv[8], wv4[8];
            *(float4*)&xv[0]  = *(const float4*)&xs[k][r0];
            *(float4*)&xv[4]  = *(const float4*)&xs[k][r0 + 4];
            *(float4*)&wv4[0] = *(const float4*)&ws[k][c0];
            *(float4*)&wv4[4] = *(const float4*)&ws[k][c1];
            #pragma unroll
            for (int i = 0; i < 8; ++i)
                #pragma unroll
                for (int j = 0; j < 8; ++j)
                    acc[i][j] = fmaf(xv[i], wv4[j], acc[i][j]);
        }
        __syncthreads();
    }

    float4 bv0 = *(const float4*)(bias + colBase + c0);
    float4 bv1 = *(const float4*)(bias + colBase + c1);
    #pragma unroll
    for (int i = 0; i < 8; ++i) {
        int row = rowsBase + r0 + i;
        float o[8];
        o[0] = acc[i][0] + bv0.x; o[1] = acc[i][1] + bv0.y;
        o[2] = acc[i][2] + bv0.z; o[3] = acc[i][3] + bv0.w;
        o[4] = acc[i][4] + bv1.x; o[5] = acc[i][5] + bv1.y;
        o[6] = acc[i][6] + bv1.z; o[7] = acc[i][7] + bv1.w;
        #pragma unroll
        for (int j = 0; j < 8; ++j)
            o[j] = (ACT == 0) ? gelu_exact(o[j]) : (1.0f / (1.0f + expf(-o[j])));
        *(float4*)(out + (size_t)row * N + colBase + c0) = *(float4*)&o[0];
        *(float4*)(out + (size_t)row * N + colBase + c1) = *(float4*)&o[4];
    }
}

// ---------------------------------------------------------------------------
// K3: logits = h2 @ w3 + b3 + gi; probs; constrained selection -> sel;
//     scalar partials. 128 threads/block (1 row/thread), 256 blocks.
// scal: [0]=active_groups [1..8]=group_usage [9]=load_balance [10]=active_dims
// ---------------------------------------------------------------------------
__global__ __launch_bounds__(128) void k3_router(
    const float* __restrict__ h2, const float* __restrict__ w3,
    const float* __restrict__ b3, const float* __restrict__ gi,
    float* __restrict__ probsOut, float* __restrict__ selOut,
    float* __restrict__ scal)
{
    __shared__ float ws3[128][8];
    __shared__ float sAct[2], sP[2], sCnt[2][8];

    const int tid = threadIdx.x;
    *(float4*)&ws3[tid][0] = *(const float4*)(w3 + tid * 8);
    *(float4*)&ws3[tid][4] = *(const float4*)(w3 + tid * 8 + 4);
    __syncthreads();

    const int row = blockIdx.x * 128 + tid;
    const float* h2r = h2 + (size_t)row * 128;

    float accg[8];
    #pragma unroll
    for (int g = 0; g < 8; ++g) accg[g] = 0.0f;
    #pragma unroll 8
    for (int k4 = 0; k4 < 32; ++k4) {
        float4 hv = *(const float4*)(h2r + k4 * 4);
        float hv4[4] = {hv.x, hv.y, hv.z, hv.w};
        #pragma unroll
        for (int t = 0; t < 4; ++t)
            #pragma unroll
            for (int g = 0; g < 8; ++g)
                accg[g] = fmaf(hv4[t], ws3[k4 * 4 + t][g], accg[g]);
    }

    float p[8], gs[8], cnt[8];
    float actCnt = 0.0f, pSum = 0.0f;
    #pragma unroll
    for (int g = 0; g < 8; ++g) {
        float lg = accg[g] + b3[g] + gi[g];
        p[g] = 1.0f / (1.0f + expf(-lg));
    }
    #pragma unroll
    for (int g = 0; g < 8; ++g) {
        int rank = 0;
        #pragma unroll
        for (int j = 0; j < 8; ++j) {
            rank += (p[j] > p[g]) ? 1 : 0;
            rank += (j < g && p[j] == p[g]) ? 1 : 0;   // stable tie-break
        }
        float act = (rank < 2) ? 1.0f
                  : ((rank < 6) ? ((p[g] > 0.5f) ? 1.0f : 0.0f) : 0.0f);
        gs[g] = (act - p[g]) + p[g];                   // STE forward, same fp32 ops as ref
        float over = (p[g] > 0.5f) ? 1.0f : 0.0f;
        cnt[g] = over;
        actCnt += over;
        pSum += p[g];
    }

    *(float4*)(probsOut + (size_t)row * 8)     = *(float4*)&p[0];
    *(float4*)(probsOut + (size_t)row * 8 + 4) = *(float4*)&p[4];
    *(float4*)(selOut   + (size_t)row * 8)     = *(float4*)&gs[0];
    *(float4*)(selOut   + (size_t)row * 8 + 4) = *(float4*)&gs[4];

    #pragma unroll
    for (int o = 32; o > 0; o >>= 1) {
        actCnt += __shfl_down(actCnt, o);
        pSum   += __shfl_down(pSum, o);
        #pragma unroll
        for (int g = 0; g < 8; ++g) cnt[g] += __shfl_down(cnt[g], o);
    }
    if ((tid & 63) == 0) {
        int w = tid >> 6;
        sAct[w] = actCnt; sP[w] = pSum;
        #pragma unroll
        for (int g = 0; g < 8; ++g) sCnt[w][g] = cnt[g];
    }
    __syncthreads();
    if (tid == 0) {
        const float invB = 1.0f / 32768.0f;
        atomicAdd(&scal[0], (sAct[0] + sAct[1]) * invB);
        atomicAdd(&scal[9], (sP[0] + sP[1]) * invB);
        #pragma unroll
        for (int g = 0; g < 8; ++g)
            atomicAdd(&scal[1 + g], (sCnt[0][g] + sCnt[1][g]) * invB);
    }
}

// ---------------------------------------------------------------------------
// K4: gmask = repeat(sel); mask = gmask * dim_weights;
//     active_dims = mean_B count(mask > 0.5)
// ---------------------------------------------------------------------------
__global__ __launch_bounds__(256) void k4_mask(
    const float* __restrict__ sel, const float* __restrict__ dwts,
    float* __restrict__ gmaskOut, float* __restrict__ maskOut,
    float* __restrict__ activeDims)
{
    const int stride = gridDim.x * 256;
    float cntF = 0.0f;
    for (int i4 = blockIdx.x * 256 + threadIdx.x; i4 < 6291456; i4 += stride) {
        int row = i4 / 192;               // 192 f4 per row
        int rem = i4 - row * 192;
        int g = rem / 24;                 // 24 f4 per group (96 floats)
        float v = sel[(size_t)row * 8 + g];
        float4 d = *(const float4*)(dwts + (size_t)i4 * 4);
        float4 gm = {v, v, v, v};
        float4 m = {v * d.x, v * d.y, v * d.z, v * d.w};
        *(float4*)(gmaskOut + (size_t)i4 * 4) = gm;
        *(float4*)(maskOut  + (size_t)i4 * 4) = m;
        cntF += (m.x > 0.5f ? 1.0f : 0.0f) + (m.y > 0.5f ? 1.0f : 0.0f)
              + (m.z > 0.5f ? 1.0f : 0.0f) + (m.w > 0.5f ? 1.0f : 0.0f);
    }
    #pragma unroll
    for (int o = 32; o > 0; o >>= 1) cntF += __shfl_down(cntF, o);
    __shared__ float sc[4];
    if ((threadIdx.x & 63) == 0) sc[threadIdx.x >> 6] = cntF;
    __syncthreads();
    if (threadIdx.x == 0)
        atomicAdd(activeDims, (sc[0] + sc[1] + sc[2] + sc[3]) * (1.0f / 32768.0f));
}

__global__ void kz_zero(float* s) { if (threadIdx.x < 11) s[threadIdx.x] = 0.0f; }

// ---------------------------------------------------------------------------
extern "C" void kernel_launch(void* const* d_in, const int* in_sizes, int n_in,
                              void* d_out, int out_size, void* d_ws, size_t ws_size,
                              hipStream_t stream)
{
    const float* x   = (const float*)d_in[0];
    const float* w1  = (const float*)d_in[1];
    const float* b1  = (const float*)d_in[2];
    const float* lng = (const float*)d_in[3];
    const float* lnb = (const float*)d_in[4];
    const float* w2  = (const float*)d_in[5];
    const float* b2  = (const float*)d_in[6];
    const float* w3  = (const float*)d_in[7];
    const float* b3  = (const float*)d_in[8];
    const float* dw1 = (const float*)d_in[9];
    const float* db1 = (const float*)d_in[10];
    const float* dw2 = (const float*)d_in[11];
    const float* db2 = (const float*)d_in[12];
    const float* gi  = (const float*)d_in[13];

    float* out   = (float*)d_out;
    float* mask  = out;                 // [B,768]
    float* gmask = out + 25165824;      // [B,768]
    float* dwts  = out + 50331648;      // [B,768]
    float* probs = out + 75497472;      // [B,8]
    float* sel   = out + 75759616;      // [B,8]
    float* scal  = out + 76021760;      // 11 scalars

    // scratch inside the mask slot (overwritten by k4 last)
    float* h1 = mask;                   // [B,256]
    float* g1 = mask + 8388608;         // [B,256]
    float* h2 = mask + 16777216;        // [B,128]

    kz_zero<<<dim3(1), dim3(64), 0, stream>>>(scal);
    k1_gemm_lnx<<<dim3(512), dim3(512), 0, stream>>>(
        x, w1, dw1, b1, db1, lng, lnb, h1, g1);
    k2_gemm<0><<<dim3(256), dim3(256), 0, stream>>>(h1, w2, b2, h2, 128, 1);
    k2_gemm<1><<<dim3(1536), dim3(256), 0, stream>>>(g1, dw2, db2, dwts, 768, 6);
    k3_router<<<dim3(256), dim3(128), 0, stream>>>(
        h2, w3, b3, gi, probs, sel, scal);
    k4_mask<<<dim3(2048), dim3(256), 0, stream>>>(sel, dwts, gmask, mask, &scal[10]);
}